// Round 5
// baseline (2856.976 us; speedup 1.0000x reference)
//
#include <hip/hip_runtime.h>
#include <math.h>

// ============================ constants ============================
constexpr int NPTS = 32768;
constexpr long long SOFF = 33554432LL;        // NPTS*64*16, start of scalar outputs

// packed-weight offsets in d_ws (floats)
constexpr int OFF_GBW       = 0;        // [64c][3ch][128r][4]
constexpr int OFF_GBOW      = 98304;    // [64c][3ch][64o][4]
constexpr int OFF_L1W       = 147456;   // [64c][3ch][64o][4]
constexpr int OFF_L2W       = 196608;   // [64c][3ch][64o][4]
constexpr int OFF_GB_S2MV   = 245760;   // [32kq][128r][4]
constexpr int OFF_GBO_S2MV  = 262144;   // [32kq][64o][4]
constexpr int OFF_GBO_MVS2S = 270336;   // [16cq][256o][4]
constexpr int OFF_GBO_S2S   = 286720;   // [32kq][256o][4]
constexpr int OFF_L1_S2MV   = 319488;   // [64kq][64o][4]
constexpr int OFF_L1_MVS2S  = 335872;   // [16cq][256o][4]
constexpr int OFF_L1_S2S    = 352256;   // [64kq][256o][4]
constexpr int OFF_L2_S2MV   = 417792;   // [64kq][64o][4]
constexpr int OFF_L2_MVS2S  = 434176;   // [16cq][128o][4]
constexpr int OFF_L2_S2S    = 442368;   // [64kq][128o][4]
constexpr int W_TOTAL       = 475136;   // floats (~1.9MB)

// ==================== compile-time GA tables ====================
namespace ga {
constexpr int MASK_OF[16] = {0,1,2,4,8,3,5,9,6,10,12,7,11,13,14,15};
constexpr int idx_of_mask(int m){ int r = 0; for(int i=0;i<16;++i) if(MASK_OF[i]==m) r=i; return r; }
constexpr int pcount(int x){ int c=0; while(x){ c += x&1; x >>= 1; } return c; }
constexpr int nswaps(int a,int b){ int s=0; a >>= 1; while(a){ s += pcount(a&b); a >>= 1; } return s; }
constexpr float rsign(int a,int b){ return (nswaps(a,b)&1) ? -1.0f : 1.0f; }
constexpr float dsign(int m){ return rsign(m, 15^m); }
struct Ent { int i, j, k; float s; };
struct GPT { Ent e[192]; };
constexpr GPT make_gp(){
  GPT t{}; int n=0;
  for(int i=0;i<16;++i) for(int j=0;j<16;++j){
    const int a=MASK_OF[i], b=MASK_OF[j];
    if((a & b & 1) != 0) continue;             // e0^2 = 0
    t.e[n].i=i; t.e[n].j=j; t.e[n].k=idx_of_mask(a^b); t.e[n].s=rsign(a,b); ++n;
  }
  return t;
}
struct JNT { Ent e[81]; };
constexpr JNT make_jn(){
  JNT t{}; int n=0;
  for(int i=0;i<16;++i) for(int j=0;j<16;++j){
    const int ci = 15 ^ MASK_OF[i], cj = 15 ^ MASK_OF[j];
    if((ci & cj) != 0) continue;               // duals must be disjoint for wedge
    const int mr = ci ^ cj, mk = 15 ^ mr;
    t.e[n].i=i; t.e[n].j=j; t.e[n].k=idx_of_mask(mk);
    t.e[n].s = dsign(MASK_OF[i]) * dsign(MASK_OF[j]) * rsign(ci,cj) * dsign(mk);
    ++n;
  }
  return t;
}
constexpr GPT GPt = make_gp();
constexpr JNT JNt = make_jn();
} // namespace ga

// ============================ helpers ============================
__device__ __forceinline__ float dot4(float4 a, float4 b){
  return fmaf(a.x,b.x, fmaf(a.y,b.y, fmaf(a.z,b.z, a.w*b.w)));
}
__device__ __forceinline__ float gelu_t(float x){
  const float u = 0.7978845608028654f * x * (1.0f + 0.044715f * x * x);
  return 0.5f * x * (1.0f + tanhf(u));
}
// y[j] += sum over basis maps: w[grade(j)]*x[j] + (e0 blades) w[5+g]*x[partner]
__device__ __forceinline__ void accum_equi(float* __restrict__ a,
                                           const float* __restrict__ w,
                                           const float* __restrict__ x){
  a[0]  = fmaf(w[0],x[0],a[0]);
  a[1]  = fmaf(w[1],x[1],fmaf(w[5],x[0],a[1]));
  a[2]  = fmaf(w[1],x[2],a[2]);
  a[3]  = fmaf(w[1],x[3],a[3]);
  a[4]  = fmaf(w[1],x[4],a[4]);
  a[5]  = fmaf(w[2],x[5],fmaf(w[6],x[2],a[5]));
  a[6]  = fmaf(w[2],x[6],fmaf(w[6],x[3],a[6]));
  a[7]  = fmaf(w[2],x[7],fmaf(w[6],x[4],a[7]));
  a[8]  = fmaf(w[2],x[8],a[8]);
  a[9]  = fmaf(w[2],x[9],a[9]);
  a[10] = fmaf(w[2],x[10],a[10]);
  a[11] = fmaf(w[3],x[11],fmaf(w[7],x[8],a[11]));
  a[12] = fmaf(w[3],x[12],fmaf(w[7],x[9],a[12]));
  a[13] = fmaf(w[3],x[13],fmaf(w[7],x[10],a[13]));
  a[14] = fmaf(w[3],x[14],a[14]);
  a[15] = fmaf(w[4],x[15],fmaf(w[8],x[14],a[15]));
}
__device__ __forceinline__ void ld16(const float* __restrict__ p, float* __restrict__ x){
  const float4 a=*(const float4*)p, b=*(const float4*)(p+4), c=*(const float4*)(p+8), d=*(const float4*)(p+12);
  x[0]=a.x; x[1]=a.y; x[2]=a.z; x[3]=a.w; x[4]=b.x; x[5]=b.y; x[6]=b.z; x[7]=b.w;
  x[8]=c.x; x[9]=c.y; x[10]=c.z; x[11]=c.w; x[12]=d.x; x[13]=d.y; x[14]=d.z; x[15]=d.w;
}
__device__ __forceinline__ void st16(float* __restrict__ p, const float* __restrict__ x){
  *(float4*)(p)    = make_float4(x[0],x[1],x[2],x[3]);
  *(float4*)(p+4)  = make_float4(x[4],x[5],x[6],x[7]);
  *(float4*)(p+8)  = make_float4(x[8],x[9],x[10],x[11]);
  *(float4*)(p+12) = make_float4(x[12],x[13],x[14],x[15]);
}

// ======================= weight repack kernel =======================
__global__ void prep_pack(
    const float* __restrict__ gb_w_mv,   const float* __restrict__ gb_w_s2mv,
    const float* __restrict__ gbo_w_mv,  const float* __restrict__ gbo_w_s2mv,
    const float* __restrict__ gbo_w_mvs2s, const float* __restrict__ gbo_w_s2s,
    const float* __restrict__ l1_w_mv,   const float* __restrict__ l1_w_s2mv,
    const float* __restrict__ l1_w_mvs2s, const float* __restrict__ l1_w_s2s,
    const float* __restrict__ l2_w_mv,   const float* __restrict__ l2_w_s2mv,
    const float* __restrict__ l2_w_mvs2s, const float* __restrict__ l2_w_s2s,
    float* __restrict__ W)
{
  const int idx = blockIdx.x * 256 + threadIdx.x;
  if (idx >= W_TOTAL) return;
  float v = 0.0f;
  if (idx < OFF_GBOW) {                       // gb_w_mv [4,32,64,9] -> [c][ch][128r][4]
    const int l=idx, j=l&3, t=l>>2, r=t&127, t2=t>>7, ch=t2%3, c=t2/3, k=ch*4+j;
    if (k < 9) v = gb_w_mv[(r*64 + c)*9 + k];
  } else if (idx < OFF_L1W) {                 // gbo_w_mv [64,64,9]
    const int l=idx-OFF_GBOW, j=l&3, t=l>>2, o=t&63, t2=t>>6, ch=t2%3, c=t2/3, k=ch*4+j;
    if (k < 9) v = gbo_w_mv[(o*64 + c)*9 + k];
  } else if (idx < OFF_L2W) {                 // l1_w_mv
    const int l=idx-OFF_L1W, j=l&3, t=l>>2, o=t&63, t2=t>>6, ch=t2%3, c=t2/3, k=ch*4+j;
    if (k < 9) v = l1_w_mv[(o*64 + c)*9 + k];
  } else if (idx < OFF_GB_S2MV) {             // l2_w_mv
    const int l=idx-OFF_L2W, j=l&3, t=l>>2, o=t&63, t2=t>>6, ch=t2%3, c=t2/3, k=ch*4+j;
    if (k < 9) v = l2_w_mv[(o*64 + c)*9 + k];
  } else if (idx < OFF_GBO_S2MV) {            // gb_w_s2mv [128r][128k] -> [kq][128r][4]
    const int l=idx-OFF_GB_S2MV, j=l&3, t=l>>2, r=t&127, kq=t>>7;
    v = gb_w_s2mv[r*128 + kq*4 + j];
  } else if (idx < OFF_GBO_MVS2S) {           // gbo_w_s2mv [64][128]
    const int l=idx-OFF_GBO_S2MV, j=l&3, t=l>>2, o=t&63, kq=t>>6;
    v = gbo_w_s2mv[o*128 + kq*4 + j];
  } else if (idx < OFF_GBO_S2S) {             // gbo_w_mvs2s [256][64]
    const int l=idx-OFF_GBO_MVS2S, j=l&3, t=l>>2, o=t&255, cq=t>>8;
    v = gbo_w_mvs2s[o*64 + cq*4 + j];
  } else if (idx < OFF_L1_S2MV) {             // gbo_w_s2s [256][128]
    const int l=idx-OFF_GBO_S2S, j=l&3, t=l>>2, o=t&255, kq=t>>8;
    v = gbo_w_s2s[o*128 + kq*4 + j];
  } else if (idx < OFF_L1_MVS2S) {            // l1_w_s2mv [64][256]
    const int l=idx-OFF_L1_S2MV, j=l&3, t=l>>2, o=t&63, kq=t>>6;
    v = l1_w_s2mv[o*256 + kq*4 + j];
  } else if (idx < OFF_L1_S2S) {              // l1_w_mvs2s [256][64]
    const int l=idx-OFF_L1_MVS2S, j=l&3, t=l>>2, o=t&255, cq=t>>8;
    v = l1_w_mvs2s[o*64 + cq*4 + j];
  } else if (idx < OFF_L2_S2MV) {             // l1_w_s2s [256][256]
    const int l=idx-OFF_L1_S2S, j=l&3, t=l>>2, o=t&255, kq=t>>8;
    v = l1_w_s2s[o*256 + kq*4 + j];
  } else if (idx < OFF_L2_MVS2S) {            // l2_w_s2mv [64][256]
    const int l=idx-OFF_L2_S2MV, j=l&3, t=l>>2, o=t&63, kq=t>>6;
    v = l2_w_s2mv[o*256 + kq*4 + j];
  } else if (idx < OFF_L2_S2S) {              // l2_w_mvs2s [128][64]
    const int l=idx-OFF_L2_MVS2S, j=l&3, t=l>>2, o=t&127, cq=t>>7;
    v = l2_w_mvs2s[o*64 + cq*4 + j];
  } else {                                    // l2_w_s2s [128][256]
    const int l=idx-OFF_L2_S2S, j=l&3, t=l>>2, o=t&127, kq=t>>7;
    v = l2_w_s2s[o*256 + kq*4 + j];
  }
  W[idx] = v;
}

// ======================= Kernel A: gb linears + GP/JOIN =======================
// 2 points/block, 256 threads. Thread = (row r in 0..127, point p in 0..1),
// ONE acc[16] per thread (~80 VGPR demand, cap 128 -> 16 waves/CU).
// Writes hidden [N][64][16] into the d_out mv region (bcd re-reads it per-tile
// into LDS before overwriting -- safe, block-local aliasing only).
__global__ __launch_bounds__(256, 2) void stage_a(
    const float* __restrict__ xin,   // [N,64,16]
    const float* __restrict__ sinp,  // [N,128]
    const float* __restrict__ gb_b_mv, const float* __restrict__ W,
    float* __restrict__ hid)         // [N,64,16] (aliases d_out mv region)
{
  __shared__ float xt[2*64*16];      // 8KB, dense (flat copy of global tile)
  __shared__ float st[2*128];        // 1KB
  __shared__ float ht[2][128][20];   // 20KB, padded rows (bank-spread)

  const int tid = threadIdx.x;
  const int n0  = blockIdx.x * 2;

  { // stage inputs
    const float4* src = (const float4*)(xin + (size_t)n0 * 1024);
    float4* dst = (float4*)xt;
    dst[tid]       = src[tid];
    dst[tid + 256] = src[tid + 256];
    if (tid < 64) ((float4*)st)[tid] = ((const float4*)(sinp + (size_t)n0 * 128))[tid];
  }
  __syncthreads();

  const int r = tid & 127;           // weight row (0..31 left, 32..63 right, 64..95 lj, 96..127 rj)
  const int p = tid >> 7;
  float acc[16];
  #pragma unroll
  for (int j = 0; j < 16; ++j) acc[j] = 0.0f;

  const float* Wg = W + OFF_GBW;
  const float* xp = xt + p * 1024;
  for (int c = 0; c < 64; ++c) {
    const float4 wa = *(const float4*)(Wg + (((c*3+0)<<7) + r)*4);
    const float4 wb = *(const float4*)(Wg + (((c*3+1)<<7) + r)*4);
    const float4 wc = *(const float4*)(Wg + (((c*3+2)<<7) + r)*4);
    const float w12[12] = {wa.x,wa.y,wa.z,wa.w, wb.x,wb.y,wb.z,wb.w, wc.x,wc.y,wc.z,wc.w};
    float xv[16];
    ld16(xp + c*16, xv);             // LDS broadcast (uniform addr per wave)
    accum_equi(acc, w12, xv);
  }
  { // scalars -> comp0 + bias
    const float* Ws = W + OFF_GB_S2MV;
    const float* sp = st + p * 128;
    for (int kq = 0; kq < 32; ++kq) {
      const float4 wq = *(const float4*)(Ws + ((kq<<7) + r)*4);
      const float4 sv = *(const float4*)(sp + (kq<<2));
      acc[0] += dot4(wq, sv);
    }
    acc[0] += gb_b_mv[r];
  }
  st16(&ht[p][r][0], acc);
  __syncthreads();

  // GP / JOIN: 128 items (2 pts x 32 GP + 2 pts x 32 JOIN), 1 per thread.
  if (tid < 128) {
    const int h  = tid & 31;
    const int pp = (tid >> 5) & 1;
    const int jn = tid >> 6;         // wave-uniform: wave0=GP, wave1=JOIN
    float L[16], R[16], o16[16];
    ld16(&ht[pp][(jn ? 64 : 0)  + h][0], L);
    ld16(&ht[pp][(jn ? 96 : 32) + h][0], R);
    #pragma unroll
    for (int j = 0; j < 16; ++j) o16[j] = 0.0f;
    if (jn == 0) {
      #pragma unroll
      for (int n = 0; n < 192; ++n)
        o16[ga::GPt.e[n].k] = fmaf(ga::GPt.e[n].s * L[ga::GPt.e[n].i], R[ga::GPt.e[n].j], o16[ga::GPt.e[n].k]);
    } else {
      #pragma unroll
      for (int n = 0; n < 81; ++n)
        o16[ga::JNt.e[n].k] = fmaf(ga::JNt.e[n].s * L[ga::JNt.e[n].i], R[ga::JNt.e[n].j], o16[ga::JNt.e[n].k]);
    }
    const int ch = (jn ? 32 : 0) + h;
    st16(hid + (((size_t)(n0 + pp) * 64) + ch) * 16, o16);
  }
}

// ======================= Kernel B/C/D: 3 linears + norms =======================
// 4 points/block, wave = point, lane = output channel. ~100 VGPR demand,
// cap 128 -> target 16 waves/CU (LDS 32KB -> 4 blocks/CU).
__global__ __launch_bounds__(256, 2) void bcd(
    const float* __restrict__ sinp,
    const float* __restrict__ gbo_b_mv, const float* __restrict__ gbo_b_s,
    const float* __restrict__ l1_b_mv,  const float* __restrict__ l1_b_s,
    const float* __restrict__ l2_b_mv,  const float* __restrict__ l2_b_s,
    const float* __restrict__ W,
    float* __restrict__ out)           // hid lives in out's mv region
{
  __shared__ float hidt[4][64][20];  // 20KB, padded
  __shared__ float s1b[4][256];      // 4KB
  __shared__ float s2b[4][256];      // 4KB
  __shared__ float c0b[4][64];       // 1KB
  __shared__ float sb[4][128];       // 2KB

  const int tid = threadIdx.x;
  const int n0  = blockIdx.x * 4;
  const float* hid = out;            // read this tile BEFORE any write to it

  { // stage hid tile (1024 float4) + scalars (128 float4)
    const float4* hsrc = (const float4*)(hid + (size_t)n0 * 1024);
    #pragma unroll
    for (int q = 0; q < 4; ++q) {
      const int i  = q * 256 + tid;
      const int pp = i >> 8, rem = i & 255, c = rem >> 2, qq = rem & 3;
      const float4 v = hsrc[i];
      *(float4*)&hidt[pp][c][qq * 4] = v;
      if (qq == 0) c0b[pp][c] = v.x;
    }
    if (tid < 128) ((float4*)sb)[tid] = ((const float4*)(sinp + (size_t)n0 * 128))[tid];
  }
  __syncthreads();

  const int o = tid & 63;
  const int p = tid >> 6;            // wave = point
  const int n = n0 + p;

  // ------------------------- Stage B: gbo linear + norms + gated gelu -------------------------
  float mvg[16];
  {
    float acc[16];
    #pragma unroll
    for(int j=0;j<16;++j) acc[j]=0.0f;
    const float* Wg = W + OFF_GBOW;
    for(int c=0;c<64;++c){
      const float4 wa = *(const float4*)(Wg + (((c*3+0)<<6) + o)*4);
      const float4 wb = *(const float4*)(Wg + (((c*3+1)<<6) + o)*4);
      const float4 wc = *(const float4*)(Wg + (((c*3+2)<<6) + o)*4);
      const float w12[12] = {wa.x,wa.y,wa.z,wa.w, wb.x,wb.y,wb.z,wb.w, wc.x,wc.y,wc.z,wc.w};
      float xv[16];
      ld16(&hidt[p][c][0], xv);
      accum_equi(acc, w12, xv);
    }
    float sacc[4] = {0.f,0.f,0.f,0.f};
    for(int kq=0;kq<32;++kq){
      const float4 sv = *(const float4*)(&sb[p][kq<<2]);
      const float4 wm = *(const float4*)(W + OFF_GBO_S2MV + (((kq<<6) + o)<<2));
      acc[0] += dot4(wm, sv);
      #pragma unroll
      for(int rr=0;rr<4;++rr){
        const float4 ws = *(const float4*)(W + OFF_GBO_S2S + (((kq<<8) + (rr<<6) + o)<<2));
        sacc[rr] += dot4(ws, sv);
      }
    }
    for(int cq=0;cq<16;++cq){
      const float4 h0 = *(const float4*)(&c0b[p][cq<<2]);
      #pragma unroll
      for(int rr=0;rr<4;++rr){
        const float4 wq = *(const float4*)(W + OFF_GBO_MVS2S + (((cq<<8) + (rr<<6) + o)<<2));
        sacc[rr] += dot4(wq, h0);
      }
    }
    acc[0] += gbo_b_mv[o];
    #pragma unroll
    for(int rr=0;rr<4;++rr) sacc[rr] += gbo_b_s[(rr<<6)+o];

    float sq = acc[0]*acc[0]+acc[2]*acc[2]+acc[3]*acc[3]+acc[4]*acc[4]
             + acc[8]*acc[8]+acc[9]*acc[9]+acc[10]*acc[10]+acc[14]*acc[14];
    #pragma unroll
    for(int m=1;m<64;m<<=1) sq += __shfl_xor(sq, m);
    const float rs = 1.0f / sqrtf(fmaxf(sq * (1.0f/64.0f), 0.01f));
    #pragma unroll
    for(int j=0;j<16;++j) acc[j] *= rs;
    const float gate = gelu_t(acc[0]);
    #pragma unroll
    for(int j=0;j<16;++j) mvg[j] = gate * acc[j];

    float sum = sacc[0]+sacc[1]+sacc[2]+sacc[3];
    float ssq = sacc[0]*sacc[0]+sacc[1]*sacc[1]+sacc[2]*sacc[2]+sacc[3]*sacc[3];
    #pragma unroll
    for(int m=1;m<64;m<<=1){ sum += __shfl_xor(sum, m); ssq += __shfl_xor(ssq, m); }
    const float mu   = sum * (1.0f/256.0f);
    const float var  = ssq * (1.0f/256.0f) - mu*mu;
    const float rstd = rsqrtf(var + 1e-5f);
    #pragma unroll
    for(int rr=0;rr<4;++rr) s1b[p][(rr<<6)+o] = gelu_t((sacc[rr]-mu)*rstd);
  }
  __syncthreads();
  st16(&hidt[p][o][0], mvg);
  c0b[p][o] = mvg[0];
  __syncthreads();

  // ------------------------- Stage C: l1 linear + norms + gated gelu -------------------------
  float mv2[16];
  {
    float acc[16];
    #pragma unroll
    for(int j=0;j<16;++j) acc[j]=0.0f;
    const float* Wg = W + OFF_L1W;
    for(int c=0;c<64;++c){
      const float4 wa = *(const float4*)(Wg + (((c*3+0)<<6) + o)*4);
      const float4 wb = *(const float4*)(Wg + (((c*3+1)<<6) + o)*4);
      const float4 wc = *(const float4*)(Wg + (((c*3+2)<<6) + o)*4);
      const float w12[12] = {wa.x,wa.y,wa.z,wa.w, wb.x,wb.y,wb.z,wb.w, wc.x,wc.y,wc.z,wc.w};
      float xv[16];
      ld16(&hidt[p][c][0], xv);
      accum_equi(acc, w12, xv);
    }
    float sacc[4] = {0.f,0.f,0.f,0.f};
    for(int kq=0;kq<64;++kq){
      const float4 sv = *(const float4*)(&s1b[p][kq<<2]);
      const float4 wm = *(const float4*)(W + OFF_L1_S2MV + (((kq<<6) + o)<<2));
      acc[0] += dot4(wm, sv);
      #pragma unroll
      for(int rr=0;rr<4;++rr){
        const float4 ws = *(const float4*)(W + OFF_L1_S2S + (((kq<<8) + (rr<<6) + o)<<2));
        sacc[rr] += dot4(ws, sv);
      }
    }
    for(int cq=0;cq<16;++cq){
      const float4 h0 = *(const float4*)(&c0b[p][cq<<2]);
      #pragma unroll
      for(int rr=0;rr<4;++rr){
        const float4 wq = *(const float4*)(W + OFF_L1_MVS2S + (((cq<<8) + (rr<<6) + o)<<2));
        sacc[rr] += dot4(wq, h0);
      }
    }
    acc[0] += l1_b_mv[o];
    #pragma unroll
    for(int rr=0;rr<4;++rr) sacc[rr] += l1_b_s[(rr<<6)+o];

    float sq = acc[0]*acc[0]+acc[2]*acc[2]+acc[3]*acc[3]+acc[4]*acc[4]
             + acc[8]*acc[8]+acc[9]*acc[9]+acc[10]*acc[10]+acc[14]*acc[14];
    #pragma unroll
    for(int m=1;m<64;m<<=1) sq += __shfl_xor(sq, m);
    const float rs = 1.0f / sqrtf(fmaxf(sq * (1.0f/64.0f), 0.01f));
    #pragma unroll
    for(int j=0;j<16;++j) acc[j] *= rs;
    const float gate = gelu_t(acc[0]);
    #pragma unroll
    for(int j=0;j<16;++j) mv2[j] = gate * acc[j];

    float sum = sacc[0]+sacc[1]+sacc[2]+sacc[3];
    float ssq = sacc[0]*sacc[0]+sacc[1]*sacc[1]+sacc[2]*sacc[2]+sacc[3]*sacc[3];
    #pragma unroll
    for(int m=1;m<64;m<<=1){ sum += __shfl_xor(sum, m); ssq += __shfl_xor(ssq, m); }
    const float mu   = sum * (1.0f/256.0f);
    const float var  = ssq * (1.0f/256.0f) - mu*mu;
    const float rstd = rsqrtf(var + 1e-5f);
    #pragma unroll
    for(int rr=0;rr<4;++rr) s2b[p][(rr<<6)+o] = gelu_t((sacc[rr]-mu)*rstd);
  }
  __syncthreads();
  st16(&hidt[p][o][0], mv2);
  c0b[p][o] = mv2[0];
  __syncthreads();

  // ------------------------- Stage D: l2 linear (plain) -> global -------------------------
  {
    float acc[16];
    #pragma unroll
    for(int j=0;j<16;++j) acc[j]=0.0f;
    const float* Wg = W + OFF_L2W;
    for(int c=0;c<64;++c){
      const float4 wa = *(const float4*)(Wg + (((c*3+0)<<6) + o)*4);
      const float4 wb = *(const float4*)(Wg + (((c*3+1)<<6) + o)*4);
      const float4 wc = *(const float4*)(Wg + (((c*3+2)<<6) + o)*4);
      const float w12[12] = {wa.x,wa.y,wa.z,wa.w, wb.x,wb.y,wb.z,wb.w, wc.x,wc.y,wc.z,wc.w};
      float xv[16];
      ld16(&hidt[p][c][0], xv);
      accum_equi(acc, w12, xv);
    }
    float sacc[2] = {0.f,0.f};
    for(int kq=0;kq<64;++kq){
      const float4 sv = *(const float4*)(&s2b[p][kq<<2]);
      const float4 wm = *(const float4*)(W + OFF_L2_S2MV + (((kq<<6) + o)<<2));
      acc[0] += dot4(wm, sv);
      #pragma unroll
      for(int rr=0;rr<2;++rr){
        const float4 ws = *(const float4*)(W + OFF_L2_S2S + (((kq<<7) + (rr<<6) + o)<<2));
        sacc[rr] += dot4(ws, sv);
      }
    }
    for(int cq=0;cq<16;++cq){
      const float4 h0 = *(const float4*)(&c0b[p][cq<<2]);
      #pragma unroll
      for(int rr=0;rr<2;++rr){
        const float4 wq = *(const float4*)(W + OFF_L2_MVS2S + (((cq<<7) + (rr<<6) + o)<<2));
        sacc[rr] += dot4(wq, h0);
      }
    }
    acc[0] += l2_b_mv[o];
    st16(out + ((size_t)n*64 + o)*16, acc);
    #pragma unroll
    for(int rr=0;rr<2;++rr){
      out[SOFF + (size_t)n*128 + (rr<<6) + o] = sacc[rr] + l2_b_s[(rr<<6)+o];
    }
  }
}

// ============================ host launch ============================
extern "C" void kernel_launch(void* const* d_in, const int* in_sizes, int n_in,
                              void* d_out, int out_size, void* d_ws, size_t ws_size,
                              hipStream_t stream) {
  const float* xin          = (const float*)d_in[0];
  const float* sinp         = (const float*)d_in[1];
  const float* gb_w_mv      = (const float*)d_in[2];
  const float* gb_w_s2mv    = (const float*)d_in[3];
  const float* gb_b_mv      = (const float*)d_in[4];
  const float* gbo_w_mv     = (const float*)d_in[5];
  const float* gbo_w_s2mv   = (const float*)d_in[6];
  const float* gbo_b_mv     = (const float*)d_in[7];
  const float* gbo_w_mvs2s  = (const float*)d_in[8];
  const float* gbo_w_s2s    = (const float*)d_in[9];
  const float* gbo_b_s      = (const float*)d_in[10];
  const float* l1_w_mv      = (const float*)d_in[11];
  const float* l1_w_s2mv    = (const float*)d_in[12];
  const float* l1_b_mv      = (const float*)d_in[13];
  const float* l1_w_mvs2s   = (const float*)d_in[14];
  const float* l1_w_s2s     = (const float*)d_in[15];
  const float* l1_b_s       = (const float*)d_in[16];
  const float* l2_w_mv      = (const float*)d_in[17];
  const float* l2_w_s2mv    = (const float*)d_in[18];
  const float* l2_b_mv      = (const float*)d_in[19];
  const float* l2_w_mvs2s   = (const float*)d_in[20];
  const float* l2_w_s2s     = (const float*)d_in[21];
  const float* l2_b_s       = (const float*)d_in[22];
  float* W   = (float*)d_ws;
  float* out = (float*)d_out;

  prep_pack<<<(W_TOTAL + 255) / 256, 256, 0, stream>>>(
      gb_w_mv, gb_w_s2mv, gbo_w_mv, gbo_w_s2mv, gbo_w_mvs2s, gbo_w_s2s,
      l1_w_mv, l1_w_s2mv, l1_w_mvs2s, l1_w_s2s,
      l2_w_mv, l2_w_s2mv, l2_w_mvs2s, l2_w_s2s, W);

  stage_a<<<NPTS / 2, 256, 0, stream>>>(xin, sinp, gb_b_mv, W, out);

  bcd<<<NPTS / 4, 256, 0, stream>>>(
      sinp, gbo_b_mv, gbo_b_s, l1_b_mv, l1_b_s, l2_b_mv, l2_b_s, W, out);
}

// Round 6
// 2021.416 us; speedup vs baseline: 1.4134x; 1.4134x over previous
//
#include <hip/hip_runtime.h>
#include <math.h>

// ============================ constants ============================
constexpr int NPTS = 32768;
constexpr long long SOFF = 33554432LL;        // NPTS*64*16, start of scalar outputs

// packed-weight offsets in d_ws (floats)
constexpr int OFF_GBW       = 0;        // [64c][3ch][128r][4]
constexpr int OFF_GBOW      = 98304;    // [64c][3ch][64o][4]
constexpr int OFF_L1W       = 147456;   // [64c][3ch][64o][4]
constexpr int OFF_L2W       = 196608;   // [64c][3ch][64o][4]
constexpr int OFF_GB_S2MV   = 245760;   // [32kq][128r][4]
constexpr int OFF_GBO_S2MV  = 262144;   // [32kq][64o][4]
constexpr int OFF_GBO_MVS2S = 270336;   // [16cq][256o][4]
constexpr int OFF_GBO_S2S   = 286720;   // [32kq][256o][4]
constexpr int OFF_L1_S2MV   = 319488;   // [64kq][64o][4]
constexpr int OFF_L1_MVS2S  = 335872;   // [16cq][256o][4]
constexpr int OFF_L1_S2S    = 352256;   // [64kq][256o][4]
constexpr int OFF_L2_S2MV   = 417792;   // [64kq][64o][4]
constexpr int OFF_L2_MVS2S  = 434176;   // [16cq][128o][4]
constexpr int OFF_L2_S2S    = 442368;   // [64kq][128o][4]
constexpr int W_TOTAL       = 475136;   // floats (~1.9MB)

// ==================== compile-time GA tables ====================
namespace ga {
constexpr int MASK_OF[16] = {0,1,2,4,8,3,5,9,6,10,12,7,11,13,14,15};
constexpr int idx_of_mask(int m){ int r = 0; for(int i=0;i<16;++i) if(MASK_OF[i]==m) r=i; return r; }
constexpr int pcount(int x){ int c=0; while(x){ c += x&1; x >>= 1; } return c; }
constexpr int nswaps(int a,int b){ int s=0; a >>= 1; while(a){ s += pcount(a&b); a >>= 1; } return s; }
constexpr float rsign(int a,int b){ return (nswaps(a,b)&1) ? -1.0f : 1.0f; }
constexpr float dsign(int m){ return rsign(m, 15^m); }
struct Ent { int i, j, k; float s; };
struct GPT { Ent e[192]; };
constexpr GPT make_gp(){
  GPT t{}; int n=0;
  for(int i=0;i<16;++i) for(int j=0;j<16;++j){
    const int a=MASK_OF[i], b=MASK_OF[j];
    if((a & b & 1) != 0) continue;             // e0^2 = 0
    t.e[n].i=i; t.e[n].j=j; t.e[n].k=idx_of_mask(a^b); t.e[n].s=rsign(a,b); ++n;
  }
  return t;
}
struct JNT { Ent e[81]; };
constexpr JNT make_jn(){
  JNT t{}; int n=0;
  for(int i=0;i<16;++i) for(int j=0;j<16;++j){
    const int ci = 15 ^ MASK_OF[i], cj = 15 ^ MASK_OF[j];
    if((ci & cj) != 0) continue;               // duals must be disjoint for wedge
    const int mr = ci ^ cj, mk = 15 ^ mr;
    t.e[n].i=i; t.e[n].j=j; t.e[n].k=idx_of_mask(mk);
    t.e[n].s = dsign(MASK_OF[i]) * dsign(MASK_OF[j]) * rsign(ci,cj) * dsign(mk);
    ++n;
  }
  return t;
}
constexpr GPT GPt = make_gp();
constexpr JNT JNt = make_jn();
} // namespace ga

// ============================ helpers ============================
__device__ __forceinline__ float dot4(float4 a, float4 b){
  return fmaf(a.x,b.x, fmaf(a.y,b.y, fmaf(a.z,b.z, a.w*b.w)));
}
__device__ __forceinline__ float gelu_t(float x){
  const float u = 0.7978845608028654f * x * (1.0f + 0.044715f * x * x);
  return 0.5f * x * (1.0f + tanhf(u));
}
__device__ __forceinline__ void accum_equi(float* __restrict__ a,
                                           const float* __restrict__ w,
                                           const float* __restrict__ x){
  a[0]  = fmaf(w[0],x[0],a[0]);
  a[1]  = fmaf(w[1],x[1],fmaf(w[5],x[0],a[1]));
  a[2]  = fmaf(w[1],x[2],a[2]);
  a[3]  = fmaf(w[1],x[3],a[3]);
  a[4]  = fmaf(w[1],x[4],a[4]);
  a[5]  = fmaf(w[2],x[5],fmaf(w[6],x[2],a[5]));
  a[6]  = fmaf(w[2],x[6],fmaf(w[6],x[3],a[6]));
  a[7]  = fmaf(w[2],x[7],fmaf(w[6],x[4],a[7]));
  a[8]  = fmaf(w[2],x[8],a[8]);
  a[9]  = fmaf(w[2],x[9],a[9]);
  a[10] = fmaf(w[2],x[10],a[10]);
  a[11] = fmaf(w[3],x[11],fmaf(w[7],x[8],a[11]));
  a[12] = fmaf(w[3],x[12],fmaf(w[7],x[9],a[12]));
  a[13] = fmaf(w[3],x[13],fmaf(w[7],x[10],a[13]));
  a[14] = fmaf(w[3],x[14],a[14]);
  a[15] = fmaf(w[4],x[15],fmaf(w[8],x[14],a[15]));
}
__device__ __forceinline__ void ld16(const float* __restrict__ p, float* __restrict__ x){
  const float4 a=*(const float4*)p, b=*(const float4*)(p+4), c=*(const float4*)(p+8), d=*(const float4*)(p+12);
  x[0]=a.x; x[1]=a.y; x[2]=a.z; x[3]=a.w; x[4]=b.x; x[5]=b.y; x[6]=b.z; x[7]=b.w;
  x[8]=c.x; x[9]=c.y; x[10]=c.z; x[11]=c.w; x[12]=d.x; x[13]=d.y; x[14]=d.z; x[15]=d.w;
}
__device__ __forceinline__ void st16(float* __restrict__ p, const float* __restrict__ x){
  *(float4*)(p)    = make_float4(x[0],x[1],x[2],x[3]);
  *(float4*)(p+4)  = make_float4(x[4],x[5],x[6],x[7]);
  *(float4*)(p+8)  = make_float4(x[8],x[9],x[10],x[11]);
  *(float4*)(p+12) = make_float4(x[12],x[13],x[14],x[15]);
}

// ======================= weight repack kernel =======================
__global__ void prep_pack(
    const float* __restrict__ gb_w_mv,   const float* __restrict__ gb_w_s2mv,
    const float* __restrict__ gbo_w_mv,  const float* __restrict__ gbo_w_s2mv,
    const float* __restrict__ gbo_w_mvs2s, const float* __restrict__ gbo_w_s2s,
    const float* __restrict__ l1_w_mv,   const float* __restrict__ l1_w_s2mv,
    const float* __restrict__ l1_w_mvs2s, const float* __restrict__ l1_w_s2s,
    const float* __restrict__ l2_w_mv,   const float* __restrict__ l2_w_s2mv,
    const float* __restrict__ l2_w_mvs2s, const float* __restrict__ l2_w_s2s,
    float* __restrict__ W)
{
  const int idx = blockIdx.x * 256 + threadIdx.x;
  if (idx >= W_TOTAL) return;
  float v = 0.0f;
  if (idx < OFF_GBOW) {
    const int l=idx, j=l&3, t=l>>2, r=t&127, t2=t>>7, ch=t2%3, c=t2/3, k=ch*4+j;
    if (k < 9) v = gb_w_mv[(r*64 + c)*9 + k];
  } else if (idx < OFF_L1W) {
    const int l=idx-OFF_GBOW, j=l&3, t=l>>2, o=t&63, t2=t>>6, ch=t2%3, c=t2/3, k=ch*4+j;
    if (k < 9) v = gbo_w_mv[(o*64 + c)*9 + k];
  } else if (idx < OFF_L2W) {
    const int l=idx-OFF_L1W, j=l&3, t=l>>2, o=t&63, t2=t>>6, ch=t2%3, c=t2/3, k=ch*4+j;
    if (k < 9) v = l1_w_mv[(o*64 + c)*9 + k];
  } else if (idx < OFF_GB_S2MV) {
    const int l=idx-OFF_L2W, j=l&3, t=l>>2, o=t&63, t2=t>>6, ch=t2%3, c=t2/3, k=ch*4+j;
    if (k < 9) v = l2_w_mv[(o*64 + c)*9 + k];
  } else if (idx < OFF_GBO_S2MV) {
    const int l=idx-OFF_GB_S2MV, j=l&3, t=l>>2, r=t&127, kq=t>>7;
    v = gb_w_s2mv[r*128 + kq*4 + j];
  } else if (idx < OFF_GBO_MVS2S) {
    const int l=idx-OFF_GBO_S2MV, j=l&3, t=l>>2, o=t&63, kq=t>>6;
    v = gbo_w_s2mv[o*128 + kq*4 + j];
  } else if (idx < OFF_GBO_S2S) {
    const int l=idx-OFF_GBO_MVS2S, j=l&3, t=l>>2, o=t&255, cq=t>>8;
    v = gbo_w_mvs2s[o*64 + cq*4 + j];
  } else if (idx < OFF_L1_S2MV) {
    const int l=idx-OFF_GBO_S2S, j=l&3, t=l>>2, o=t&255, kq=t>>8;
    v = gbo_w_s2s[o*128 + kq*4 + j];
  } else if (idx < OFF_L1_MVS2S) {
    const int l=idx-OFF_L1_S2MV, j=l&3, t=l>>2, o=t&63, kq=t>>6;
    v = l1_w_s2mv[o*256 + kq*4 + j];
  } else if (idx < OFF_L1_S2S) {
    const int l=idx-OFF_L1_MVS2S, j=l&3, t=l>>2, o=t&255, cq=t>>8;
    v = l1_w_mvs2s[o*64 + cq*4 + j];
  } else if (idx < OFF_L2_S2MV) {
    const int l=idx-OFF_L1_S2S, j=l&3, t=l>>2, o=t&255, kq=t>>8;
    v = l1_w_s2s[o*256 + kq*4 + j];
  } else if (idx < OFF_L2_MVS2S) {
    const int l=idx-OFF_L2_S2MV, j=l&3, t=l>>2, o=t&63, kq=t>>6;
    v = l2_w_s2mv[o*256 + kq*4 + j];
  } else if (idx < OFF_L2_S2S) {
    const int l=idx-OFF_L2_MVS2S, j=l&3, t=l>>2, o=t&127, cq=t>>7;
    v = l2_w_mvs2s[o*64 + cq*4 + j];
  } else {
    const int l=idx-OFF_L2_S2S, j=l&3, t=l>>2, o=t&127, kq=t>>7;
    v = l2_w_s2s[o*256 + kq*4 + j];
  }
  W[idx] = v;
}

// ======================= Kernel A: gb linears + GP/JOIN =======================
// 8 points/block, 256 threads. Thread = (row r in 0..127, pg in 0..1) and owns
// FOUR points (pg*4 .. pg*4+3): weight loads amortized x4 in registers.
// acc[4][16] fully statically indexed. Cap 256 VGPR (launch_bounds min_waves=1).
// LDS: 64KB union -- phase1: xt[8][1024] @0 + st[8][128] @8192; phase2: ht[8][128][16].
__global__ __launch_bounds__(256, 1) void stage_a(
    const float* __restrict__ xin,   // [N,64,16]
    const float* __restrict__ sinp,  // [N,128]
    const float* __restrict__ gb_b_mv, const float* __restrict__ W,
    float* __restrict__ hid)         // [N,64,16] (aliases d_out mv region)
{
  __shared__ float smem[16384];      // 64 KB -> 2 blocks/CU

  const int tid = threadIdx.x;
  const int n0  = blockIdx.x * 8;

  { // stage inputs: xt = 2048 float4, st = 256 float4
    const float4* src = (const float4*)(xin + (size_t)n0 * 1024);
    float4* dst = (float4*)smem;
    #pragma unroll
    for (int q = 0; q < 8; ++q) dst[q * 256 + tid] = src[q * 256 + tid];
    ((float4*)(smem + 8192))[tid] = ((const float4*)(sinp + (size_t)n0 * 128))[tid];
  }
  __syncthreads();

  const int r  = tid & 127;          // 0..31 left, 32..63 right, 64..95 lj, 96..127 rj
  const int pg = tid >> 7;           // point group (4 points each)
  float acc[4][16];
  #pragma unroll
  for (int i = 0; i < 4; ++i)
    #pragma unroll
    for (int j = 0; j < 16; ++j) acc[i][j] = 0.0f;

  const float* Wg = W + OFF_GBW;
  const float* xp = smem + pg * 4096;          // 4 points x 1024
  for (int c = 0; c < 64; ++c) {
    const float4 wa = *(const float4*)(Wg + (((c*3+0)<<7) + r)*4);
    const float4 wb = *(const float4*)(Wg + (((c*3+1)<<7) + r)*4);
    const float4 wc = *(const float4*)(Wg + (((c*3+2)<<7) + r)*4);
    const float w12[12] = {wa.x,wa.y,wa.z,wa.w, wb.x,wb.y,wb.z,wb.w, wc.x,wc.y,wc.z,wc.w};
    #pragma unroll
    for (int i = 0; i < 4; ++i) {
      float xv[16];
      ld16(xp + i*1024 + c*16, xv);            // wave-uniform addr -> LDS broadcast
      accum_equi(acc[i], w12, xv);
    }
  }
  { // scalars -> comp0 + bias
    const float* Ws = W + OFF_GB_S2MV;
    const float* sp = smem + 8192 + pg * 512;
    for (int kq = 0; kq < 32; ++kq) {
      const float4 wq = *(const float4*)(Ws + ((kq<<7) + r)*4);
      #pragma unroll
      for (int i = 0; i < 4; ++i) {
        const float4 sv = *(const float4*)(sp + i*128 + (kq<<2));
        acc[i][0] += dot4(wq, sv);
      }
    }
    const float bias = gb_b_mv[r];
    #pragma unroll
    for (int i = 0; i < 4; ++i) acc[i][0] += bias;
  }
  __syncthreads();                   // xt/st reads done; reuse smem as ht[8][128][16]
  #pragma unroll
  for (int i = 0; i < 4; ++i)
    st16(smem + ((pg*4 + i)*128 + r)*16, acc[i]);
  __syncthreads();

  // GP + JOIN: every thread does one GP item and one JOIN item (no divergence).
  {
    const int h  = tid & 31;
    const int pp = tid >> 5;         // 0..7
    float L[16], R[16], o16[16];
    // GP(left,right) -> channel h
    ld16(smem + (pp*128 + h)*16, L);
    ld16(smem + (pp*128 + 32 + h)*16, R);
    #pragma unroll
    for (int j = 0; j < 16; ++j) o16[j] = 0.0f;
    #pragma unroll
    for (int n = 0; n < 192; ++n)
      o16[ga::GPt.e[n].k] = fmaf(ga::GPt.e[n].s * L[ga::GPt.e[n].i], R[ga::GPt.e[n].j], o16[ga::GPt.e[n].k]);
    st16(hid + (((size_t)(n0 + pp) * 64) + h) * 16, o16);
    // JOIN(lj,rj) -> channel 32+h (ref_pss = 1)
    ld16(smem + (pp*128 + 64 + h)*16, L);
    ld16(smem + (pp*128 + 96 + h)*16, R);
    #pragma unroll
    for (int j = 0; j < 16; ++j) o16[j] = 0.0f;
    #pragma unroll
    for (int n = 0; n < 81; ++n)
      o16[ga::JNt.e[n].k] = fmaf(ga::JNt.e[n].s * L[ga::JNt.e[n].i], R[ga::JNt.e[n].j], o16[ga::JNt.e[n].k]);
    st16(hid + (((size_t)(n0 + pp) * 64) + 32 + h) * 16, o16);
  }
}

// ======================= Kernel B/C/D: 3 linears + norms =======================
// SINGLE-WAVE blocks: 64 threads, 4 points. lane = output channel o; each thread
// computes all 4 points (weights amortized x4 in registers). All inter-point
// traffic (norm shuffles, s-buffers, hidt) is wave-internal. LDS 20KB -> 8 blk/CU.
__global__ __launch_bounds__(64, 1) void bcd(
    const float* __restrict__ sinp,
    const float* __restrict__ gbo_b_mv, const float* __restrict__ gbo_b_s,
    const float* __restrict__ l1_b_mv,  const float* __restrict__ l1_b_s,
    const float* __restrict__ l2_b_mv,  const float* __restrict__ l2_b_s,
    const float* __restrict__ W,
    float* __restrict__ out)           // hid lives in out's mv region
{
  __shared__ float hidt[4][64][16];  // 16 KB; reads are wave-uniform broadcasts
  __shared__ float sreg[4][256];     // 4 KB; serves s1b then s2b

  const int o  = threadIdx.x;        // 0..63
  const int n0 = blockIdx.x * 4;
  const float* hid = out;

  { // stage hid tile (1024 float4; read own tile BEFORE any write to it)
    const float4* hsrc = (const float4*)(hid + (size_t)n0 * 1024);
    float4* hdst = (float4*)hidt;
    #pragma unroll
    for (int q = 0; q < 16; ++q) hdst[q * 64 + o] = hsrc[q * 64 + o];
  }
  __syncthreads();

  // ------------------ Stage B: gbo linear + norms + gated gelu ------------------
  {
    float acc[4][16];
    #pragma unroll
    for (int i = 0; i < 4; ++i)
      #pragma unroll
      for (int j = 0; j < 16; ++j) acc[i][j] = 0.0f;
    const float* Wg = W + OFF_GBOW;
    for (int c = 0; c < 64; ++c) {
      const float4 wa = *(const float4*)(Wg + (((c*3+0)<<6) + o)*4);
      const float4 wb = *(const float4*)(Wg + (((c*3+1)<<6) + o)*4);
      const float4 wc = *(const float4*)(Wg + (((c*3+2)<<6) + o)*4);
      const float w12[12] = {wa.x,wa.y,wa.z,wa.w, wb.x,wb.y,wb.z,wb.w, wc.x,wc.y,wc.z,wc.w};
      #pragma unroll
      for (int i = 0; i < 4; ++i) {
        float xv[16];
        ld16(&hidt[i][c][0], xv);
        accum_equi(acc[i], w12, xv);
      }
    }
    float sacc[4][4];
    #pragma unroll
    for (int i = 0; i < 4; ++i)
      #pragma unroll
      for (int rr = 0; rr < 4; ++rr) sacc[i][rr] = 0.0f;
    for (int kq = 0; kq < 32; ++kq) {
      const float4 wm  = *(const float4*)(W + OFF_GBO_S2MV + (((kq<<6) + o)<<2));
      const float4 ws0 = *(const float4*)(W + OFF_GBO_S2S + (((kq<<8) + (0<<6) + o)<<2));
      const float4 ws1 = *(const float4*)(W + OFF_GBO_S2S + (((kq<<8) + (1<<6) + o)<<2));
      const float4 ws2 = *(const float4*)(W + OFF_GBO_S2S + (((kq<<8) + (2<<6) + o)<<2));
      const float4 ws3 = *(const float4*)(W + OFF_GBO_S2S + (((kq<<8) + (3<<6) + o)<<2));
      #pragma unroll
      for (int i = 0; i < 4; ++i) {
        const float4 sv = *(const float4*)(sinp + (size_t)(n0 + i)*128 + (kq<<2));
        acc[i][0]  += dot4(wm, sv);
        sacc[i][0] += dot4(ws0, sv);
        sacc[i][1] += dot4(ws1, sv);
        sacc[i][2] += dot4(ws2, sv);
        sacc[i][3] += dot4(ws3, sv);
      }
    }
    for (int cq = 0; cq < 16; ++cq) {
      const float4 wq0 = *(const float4*)(W + OFF_GBO_MVS2S + (((cq<<8) + (0<<6) + o)<<2));
      const float4 wq1 = *(const float4*)(W + OFF_GBO_MVS2S + (((cq<<8) + (1<<6) + o)<<2));
      const float4 wq2 = *(const float4*)(W + OFF_GBO_MVS2S + (((cq<<8) + (2<<6) + o)<<2));
      const float4 wq3 = *(const float4*)(W + OFF_GBO_MVS2S + (((cq<<8) + (3<<6) + o)<<2));
      #pragma unroll
      for (int i = 0; i < 4; ++i) {
        const float4 h0 = make_float4(hidt[i][(cq<<2)+0][0], hidt[i][(cq<<2)+1][0],
                                      hidt[i][(cq<<2)+2][0], hidt[i][(cq<<2)+3][0]);
        sacc[i][0] += dot4(wq0, h0);
        sacc[i][1] += dot4(wq1, h0);
        sacc[i][2] += dot4(wq2, h0);
        sacc[i][3] += dot4(wq3, h0);
      }
    }
    const float bmv = gbo_b_mv[o];
    float bs[4];
    #pragma unroll
    for (int rr = 0; rr < 4; ++rr) bs[rr] = gbo_b_s[(rr<<6)+o];
    float s1v[4][4];
    #pragma unroll
    for (int i = 0; i < 4; ++i) {
      acc[i][0] += bmv;
      #pragma unroll
      for (int rr = 0; rr < 4; ++rr) sacc[i][rr] += bs[rr];
      // equi layer norm + gated gelu (in place)
      float sq = acc[i][0]*acc[i][0]+acc[i][2]*acc[i][2]+acc[i][3]*acc[i][3]+acc[i][4]*acc[i][4]
               + acc[i][8]*acc[i][8]+acc[i][9]*acc[i][9]+acc[i][10]*acc[i][10]+acc[i][14]*acc[i][14];
      #pragma unroll
      for (int m = 1; m < 64; m <<= 1) sq += __shfl_xor(sq, m);
      const float rs = 1.0f / sqrtf(fmaxf(sq * (1.0f/64.0f), 0.01f));
      #pragma unroll
      for (int j = 0; j < 16; ++j) acc[i][j] *= rs;
      const float gate = gelu_t(acc[i][0]);
      #pragma unroll
      for (int j = 0; j < 16; ++j) acc[i][j] *= gate;
      // scalar layer norm (256) + gelu
      float sum = sacc[i][0]+sacc[i][1]+sacc[i][2]+sacc[i][3];
      float ssq = sacc[i][0]*sacc[i][0]+sacc[i][1]*sacc[i][1]+sacc[i][2]*sacc[i][2]+sacc[i][3]*sacc[i][3];
      #pragma unroll
      for (int m = 1; m < 64; m <<= 1) { sum += __shfl_xor(sum, m); ssq += __shfl_xor(ssq, m); }
      const float mu   = sum * (1.0f/256.0f);
      const float var  = ssq * (1.0f/256.0f) - mu*mu;
      const float rstd = rsqrtf(var + 1e-5f);
      #pragma unroll
      for (int rr = 0; rr < 4; ++rr) s1v[i][rr] = gelu_t((sacc[i][rr]-mu)*rstd);
    }
    __syncthreads();
    #pragma unroll
    for (int i = 0; i < 4; ++i) {
      st16(&hidt[i][o][0], acc[i]);
      #pragma unroll
      for (int rr = 0; rr < 4; ++rr) sreg[i][(rr<<6)+o] = s1v[i][rr];
    }
    __syncthreads();
  }

  // ------------------ Stage C: l1 linear + norms + gated gelu ------------------
  {
    float acc[4][16];
    #pragma unroll
    for (int i = 0; i < 4; ++i)
      #pragma unroll
      for (int j = 0; j < 16; ++j) acc[i][j] = 0.0f;
    const float* Wg = W + OFF_L1W;
    for (int c = 0; c < 64; ++c) {
      const float4 wa = *(const float4*)(Wg + (((c*3+0)<<6) + o)*4);
      const float4 wb = *(const float4*)(Wg + (((c*3+1)<<6) + o)*4);
      const float4 wc = *(const float4*)(Wg + (((c*3+2)<<6) + o)*4);
      const float w12[12] = {wa.x,wa.y,wa.z,wa.w, wb.x,wb.y,wb.z,wb.w, wc.x,wc.y,wc.z,wc.w};
      #pragma unroll
      for (int i = 0; i < 4; ++i) {
        float xv[16];
        ld16(&hidt[i][c][0], xv);
        accum_equi(acc[i], w12, xv);
      }
    }
    float sacc[4][4];
    #pragma unroll
    for (int i = 0; i < 4; ++i)
      #pragma unroll
      for (int rr = 0; rr < 4; ++rr) sacc[i][rr] = 0.0f;
    for (int kq = 0; kq < 64; ++kq) {
      const float4 wm  = *(const float4*)(W + OFF_L1_S2MV + (((kq<<6) + o)<<2));
      const float4 ws0 = *(const float4*)(W + OFF_L1_S2S + (((kq<<8) + (0<<6) + o)<<2));
      const float4 ws1 = *(const float4*)(W + OFF_L1_S2S + (((kq<<8) + (1<<6) + o)<<2));
      const float4 ws2 = *(const float4*)(W + OFF_L1_S2S + (((kq<<8) + (2<<6) + o)<<2));
      const float4 ws3 = *(const float4*)(W + OFF_L1_S2S + (((kq<<8) + (3<<6) + o)<<2));
      #pragma unroll
      for (int i = 0; i < 4; ++i) {
        const float4 sv = *(const float4*)(&sreg[i][kq<<2]);
        acc[i][0]  += dot4(wm, sv);
        sacc[i][0] += dot4(ws0, sv);
        sacc[i][1] += dot4(ws1, sv);
        sacc[i][2] += dot4(ws2, sv);
        sacc[i][3] += dot4(ws3, sv);
      }
    }
    for (int cq = 0; cq < 16; ++cq) {
      const float4 wq0 = *(const float4*)(W + OFF_L1_MVS2S + (((cq<<8) + (0<<6) + o)<<2));
      const float4 wq1 = *(const float4*)(W + OFF_L1_MVS2S + (((cq<<8) + (1<<6) + o)<<2));
      const float4 wq2 = *(const float4*)(W + OFF_L1_MVS2S + (((cq<<8) + (2<<6) + o)<<2));
      const float4 wq3 = *(const float4*)(W + OFF_L1_MVS2S + (((cq<<8) + (3<<6) + o)<<2));
      #pragma unroll
      for (int i = 0; i < 4; ++i) {
        const float4 h0 = make_float4(hidt[i][(cq<<2)+0][0], hidt[i][(cq<<2)+1][0],
                                      hidt[i][(cq<<2)+2][0], hidt[i][(cq<<2)+3][0]);
        sacc[i][0] += dot4(wq0, h0);
        sacc[i][1] += dot4(wq1, h0);
        sacc[i][2] += dot4(wq2, h0);
        sacc[i][3] += dot4(wq3, h0);
      }
    }
    const float bmv = l1_b_mv[o];
    float bs[4];
    #pragma unroll
    for (int rr = 0; rr < 4; ++rr) bs[rr] = l1_b_s[(rr<<6)+o];
    float s2v[4][4];
    #pragma unroll
    for (int i = 0; i < 4; ++i) {
      acc[i][0] += bmv;
      #pragma unroll
      for (int rr = 0; rr < 4; ++rr) sacc[i][rr] += bs[rr];
      float sq = acc[i][0]*acc[i][0]+acc[i][2]*acc[i][2]+acc[i][3]*acc[i][3]+acc[i][4]*acc[i][4]
               + acc[i][8]*acc[i][8]+acc[i][9]*acc[i][9]+acc[i][10]*acc[i][10]+acc[i][14]*acc[i][14];
      #pragma unroll
      for (int m = 1; m < 64; m <<= 1) sq += __shfl_xor(sq, m);
      const float rs = 1.0f / sqrtf(fmaxf(sq * (1.0f/64.0f), 0.01f));
      #pragma unroll
      for (int j = 0; j < 16; ++j) acc[i][j] *= rs;
      const float gate = gelu_t(acc[i][0]);
      #pragma unroll
      for (int j = 0; j < 16; ++j) acc[i][j] *= gate;
      float sum = sacc[i][0]+sacc[i][1]+sacc[i][2]+sacc[i][3];
      float ssq = sacc[i][0]*sacc[i][0]+sacc[i][1]*sacc[i][1]+sacc[i][2]*sacc[i][2]+sacc[i][3]*sacc[i][3];
      #pragma unroll
      for (int m = 1; m < 64; m <<= 1) { sum += __shfl_xor(sum, m); ssq += __shfl_xor(ssq, m); }
      const float mu   = sum * (1.0f/256.0f);
      const float var  = ssq * (1.0f/256.0f) - mu*mu;
      const float rstd = rsqrtf(var + 1e-5f);
      #pragma unroll
      for (int rr = 0; rr < 4; ++rr) s2v[i][rr] = gelu_t((sacc[i][rr]-mu)*rstd);
    }
    __syncthreads();
    #pragma unroll
    for (int i = 0; i < 4; ++i) {
      st16(&hidt[i][o][0], acc[i]);
      #pragma unroll
      for (int rr = 0; rr < 4; ++rr) sreg[i][(rr<<6)+o] = s2v[i][rr];
    }
    __syncthreads();
  }

  // ------------------ Stage D: l2 linear (plain) -> global ------------------
  {
    float acc[4][16];
    #pragma unroll
    for (int i = 0; i < 4; ++i)
      #pragma unroll
      for (int j = 0; j < 16; ++j) acc[i][j] = 0.0f;
    const float* Wg = W + OFF_L2W;
    for (int c = 0; c < 64; ++c) {
      const float4 wa = *(const float4*)(Wg + (((c*3+0)<<6) + o)*4);
      const float4 wb = *(const float4*)(Wg + (((c*3+1)<<6) + o)*4);
      const float4 wc = *(const float4*)(Wg + (((c*3+2)<<6) + o)*4);
      const float w12[12] = {wa.x,wa.y,wa.z,wa.w, wb.x,wb.y,wb.z,wb.w, wc.x,wc.y,wc.z,wc.w};
      #pragma unroll
      for (int i = 0; i < 4; ++i) {
        float xv[16];
        ld16(&hidt[i][c][0], xv);
        accum_equi(acc[i], w12, xv);
      }
    }
    float sacc[4][2];
    #pragma unroll
    for (int i = 0; i < 4; ++i) { sacc[i][0] = 0.0f; sacc[i][1] = 0.0f; }
    for (int kq = 0; kq < 64; ++kq) {
      const float4 wm  = *(const float4*)(W + OFF_L2_S2MV + (((kq<<6) + o)<<2));
      const float4 ws0 = *(const float4*)(W + OFF_L2_S2S + (((kq<<7) + (0<<6) + o)<<2));
      const float4 ws1 = *(const float4*)(W + OFF_L2_S2S + (((kq<<7) + (1<<6) + o)<<2));
      #pragma unroll
      for (int i = 0; i < 4; ++i) {
        const float4 sv = *(const float4*)(&sreg[i][kq<<2]);
        acc[i][0]  += dot4(wm, sv);
        sacc[i][0] += dot4(ws0, sv);
        sacc[i][1] += dot4(ws1, sv);
      }
    }
    for (int cq = 0; cq < 16; ++cq) {
      const float4 wq0 = *(const float4*)(W + OFF_L2_MVS2S + (((cq<<7) + (0<<6) + o)<<2));
      const float4 wq1 = *(const float4*)(W + OFF_L2_MVS2S + (((cq<<7) + (1<<6) + o)<<2));
      #pragma unroll
      for (int i = 0; i < 4; ++i) {
        const float4 h0 = make_float4(hidt[i][(cq<<2)+0][0], hidt[i][(cq<<2)+1][0],
                                      hidt[i][(cq<<2)+2][0], hidt[i][(cq<<2)+3][0]);
        sacc[i][0] += dot4(wq0, h0);
        sacc[i][1] += dot4(wq1, h0);
      }
    }
    const float bmv = l2_b_mv[o];
    const float bs0 = l2_b_s[o], bs1 = l2_b_s[64+o];
    #pragma unroll
    for (int i = 0; i < 4; ++i) {
      acc[i][0] += bmv;
      st16(out + ((size_t)(n0+i)*64 + o)*16, acc[i]);
      out[SOFF + (size_t)(n0+i)*128 + o]      = sacc[i][0] + bs0;
      out[SOFF + (size_t)(n0+i)*128 + 64 + o] = sacc[i][1] + bs1;
    }
  }
}

// ============================ host launch ============================
extern "C" void kernel_launch(void* const* d_in, const int* in_sizes, int n_in,
                              void* d_out, int out_size, void* d_ws, size_t ws_size,
                              hipStream_t stream) {
  const float* xin          = (const float*)d_in[0];
  const float* sinp         = (const float*)d_in[1];
  const float* gb_w_mv      = (const float*)d_in[2];
  const float* gb_w_s2mv    = (const float*)d_in[3];
  const float* gb_b_mv      = (const float*)d_in[4];
  const float* gbo_w_mv     = (const float*)d_in[5];
  const float* gbo_w_s2mv   = (const float*)d_in[6];
  const float* gbo_b_mv     = (const float*)d_in[7];
  const float* gbo_w_mvs2s  = (const float*)d_in[8];
  const float* gbo_w_s2s    = (const float*)d_in[9];
  const float* gbo_b_s      = (const float*)d_in[10];
  const float* l1_w_mv      = (const float*)d_in[11];
  const float* l1_w_s2mv    = (const float*)d_in[12];
  const float* l1_b_mv      = (const float*)d_in[13];
  const float* l1_w_mvs2s   = (const float*)d_in[14];
  const float* l1_w_s2s     = (const float*)d_in[15];
  const float* l1_b_s       = (const float*)d_in[16];
  const float* l2_w_mv      = (const float*)d_in[17];
  const float* l2_w_s2mv    = (const float*)d_in[18];
  const float* l2_b_mv      = (const float*)d_in[19];
  const float* l2_w_mvs2s   = (const float*)d_in[20];
  const float* l2_w_s2s     = (const float*)d_in[21];
  const float* l2_b_s       = (const float*)d_in[22];
  float* W   = (float*)d_ws;
  float* out = (float*)d_out;

  prep_pack<<<(W_TOTAL + 255) / 256, 256, 0, stream>>>(
      gb_w_mv, gb_w_s2mv, gbo_w_mv, gbo_w_s2mv, gbo_w_mvs2s, gbo_w_s2s,
      l1_w_mv, l1_w_s2mv, l1_w_mvs2s, l1_w_s2s,
      l2_w_mv, l2_w_s2mv, l2_w_mvs2s, l2_w_s2s, W);

  stage_a<<<NPTS / 8, 256, 0, stream>>>(xin, sinp, gb_b_mv, W, out);

  bcd<<<NPTS / 4, 64, 0, stream>>>(
      sinp, gbo_b_mv, gbo_b_s, l1_b_mv, l1_b_s, l2_b_mv, l2_b_s, W, out);
}